// Round 11
// baseline (518.240 us; speedup 1.0000x reference)
//
#include <hip/hip_runtime.h>
#include <cstdint>
#include <cstddef>

typedef unsigned short u16;
typedef unsigned int   u32;
typedef __attribute__((ext_vector_type(8))) short bf16x8;    // 8 bf16 in 4 VGPRs
typedef __attribute__((ext_vector_type(4))) float f32x4;
typedef __attribute__((ext_vector_type(16))) float f32x16;

#define ALPHA 0.05f
#define OMA   0.95f

__device__ __forceinline__ u16 f2b(float f) {
  u32 u = __float_as_uint(f);
  u = (u + 0x7fffu + ((u >> 16) & 1u)) >> 16;   // RNE f32->bf16
  return (u16)u;
}

__device__ __forceinline__ void gld16(const void* g, void* l) {
  __builtin_amdgcn_global_load_lds((const __attribute__((address_space(1))) u32*)g,
                                   (__attribute__((address_space(3))) u32*)l, 16, 0, 0);
}

// ---------------------------------------------------------------------------
// K0: Abar = 0.95 * rownorm(adj + I) -> fp32 Af
// ---------------------------------------------------------------------------
__global__ __launch_bounds__(256) void k_norm(const float* __restrict__ adj,
                                              float* __restrict__ Af) {
  int v = blockIdx.x;      // 512
  int t = threadIdx.x;     // 256
  float a0 = adj[(size_t)v * 512 + t]       + (t == v ? 1.f : 0.f);
  float a1 = adj[(size_t)v * 512 + t + 256] + (t + 256 == v ? 1.f : 0.f);
  float s = a0 + a1;
  for (int off = 32; off; off >>= 1) s += __shfl_down(s, off);
  __shared__ float ws4[4];
  if ((t & 63) == 0) ws4[t >> 6] = s;
  __syncthreads();
  float inv = OMA / (ws4[0] + ws4[1] + ws4[2] + ws4[3]);
  Af[(size_t)v * 512 + t]       = a0 * inv;
  Af[(size_t)v * 512 + t + 256] = a1 * inv;
}

// ---------------------------------------------------------------------------
// K1/K2: P = L @ R (512x512 fp32)
// ---------------------------------------------------------------------------
__global__ __launch_bounds__(256) void k_pow(const float* __restrict__ L,
                                             const float* __restrict__ R,
                                             float* __restrict__ Pf) {
  __shared__ float lrow[4][512];
  int r0 = blockIdx.x * 4;   // 128 blocks
  int t = threadIdx.x;       // 256
  for (int i = t; i < 4 * 512; i += 256)
    lrow[i >> 9][i & 511] = L[(size_t)(r0 + (i >> 9)) * 512 + (i & 511)];
  __syncthreads();
  float acc[4][2] = {};
  for (int k = 0; k < 512; ++k) {
    float rk0 = R[(size_t)k * 512 + t];
    float rk1 = R[(size_t)k * 512 + t + 256];
#pragma unroll
    for (int r = 0; r < 4; ++r) {
      float lv = lrow[r][k];
      acc[r][0] += lv * rk0;
      acc[r][1] += lv * rk1;
    }
  }
  for (int r = 0; r < 4; ++r) {
    Pf[(size_t)(r0 + r) * 512 + t]       = acc[r][0];
    Pf[(size_t)(r0 + r) * 512 + t + 256] = acc[r][1];
  }
}

// ---------------------------------------------------------------------------
// K3: assemble G[v][w*4+jj] = {I, Abar, Abar^2, Abar^3}[v][w]  (bf16, 512x2048)
// ---------------------------------------------------------------------------
__global__ __launch_bounds__(256) void k_pack(const float* __restrict__ A1,
                                              const float* __restrict__ A2,
                                              const float* __restrict__ A3,
                                              u16* __restrict__ G) {
  int v = blockIdx.x;      // 512
  int t = threadIdx.x;     // 256
#pragma unroll
  for (int h = 0; h < 2; ++h) {
    int w = t + h * 256;
    size_t i = (size_t)v * 512 + w;
    u32 lo = (u32)(w == v ? 0x3F80u : 0u) | ((u32)f2b(A1[i]) << 16);
    u32 hi = (u32)f2b(A2[i]) | ((u32)f2b(A3[i]) << 16);
    *(uint2*)(G + (size_t)v * 2048 + w * 4) = make_uint2(lo, hi);
  }
}

// ---------------------------------------------------------------------------
// K4: U[R=o*4+jj][c]  (bf16, 128x32) from W[32][128]
// ---------------------------------------------------------------------------
__global__ void k_u(const float* __restrict__ W, u16* __restrict__ U) {
  int R = threadIdx.x;   // 128
  int o = R >> 2, j = R & 3;
  for (int c = 0; c < 32; ++c) {
    float w0 = W[o * 128 + c];
    float w1 = W[o * 128 + 32 + c];
    float w2 = W[o * 128 + 64 + c];
    float w3 = W[o * 128 + 96 + c];
    float u;
    if (j == 0)      u = w0 + ALPHA * (w1 + w2 + w3);
    else if (j == 1) u = w1 + ALPHA * (w2 + w3);
    else if (j == 2) u = w2 + ALPHA * w3;
    else             u = w3;
    U[R * 32 + c] = f2b(u);
  }
}

// ---------------------------------------------------------------------------
// P1 (k_mix): C_jj = U_jj @ x; lane's 4 regs (jj=0..3) -> one 8-B store.
// Two v-blocks per block with reg pipeline (R9, best measured).
// ---------------------------------------------------------------------------
__global__ __launch_bounds__(256) void k_mix(const float* __restrict__ x,
                                             const u16* __restrict__ Uw,
                                             u16* __restrict__ C,
                                             int n0) {
  __shared__ u16 slab[512 * 32];   // [p][c], p = l*16 + v   (32 KB)
  __shared__ u16 Ul[128 * 32];     // [R][c]                 (8 KB)
  int t = threadIdx.x;
  int chunk = gridDim.x >> 3;
  int rb = blockIdx.x;
  int vp = (rb & 7) * chunk + (rb >> 3);
  int tile0 = vp * 2;              // even: pair shares n and l0, v0 and v0+16
  int q  = tile0 & 511;
  int n  = n0 + (tile0 >> 9);
  int v0 = (q & 31) << 4;          // v-block of 16 (even slot)
  int l0 = (q >> 5) << 5;          // l-block of 32

  gld16(Uw + t * 8,        (char*)Ul + ((t >> 6) << 10));
  gld16(Uw + 2048 + t * 8, (char*)Ul + 4096 + ((t >> 6) << 10));

  int c = t & 31;
  int v = t >> 5;   // 0..7
  const float* xbase = x + (((size_t)(n * 32 + c) * 512 + v0) << 9) + l0;

  // preload tile A (v0) into regs
  float4 r[16];
#pragma unroll
  for (int h = 0; h < 2; ++h)
#pragma unroll
    for (int f = 0; f < 8; ++f)
      r[h * 8 + f] = *(const float4*)(xbase + ((size_t)(v + h * 8) << 9) + f * 4);

  int lane = t & 63, wid = t >> 6;
  int l15 = lane & 15, g = lane >> 4;
  int nol_base = (n - n0) * 32;

  for (int half = 0; half < 2; ++half) {
    // regs -> slab (bf16, [p][c] with p = l*16 + v)
#pragma unroll
    for (int h = 0; h < 2; ++h)
#pragma unroll
      for (int f = 0; f < 8; ++f) {
        float4 d = r[h * 8 + f];
        int vv = v + h * 8;
        int p = (f * 4) * 16 + vv;
        slab[(p + 0)  * 32 + c] = f2b(d.x);
        slab[(p + 16) * 32 + c] = f2b(d.y);
        slab[(p + 32) * 32 + c] = f2b(d.z);
        slab[(p + 48) * 32 + c] = f2b(d.w);
      }
    __syncthreads();   // slab ready (also drains U gld16 on half 0)

    if (half == 0) {
      // issue tile B (v0+16) loads; they land under A's compute/stores
#pragma unroll
      for (int h = 0; h < 2; ++h)
#pragma unroll
        for (int f = 0; f < 8; ++f)
          r[h * 8 + f] = *(const float4*)(xbase + ((size_t)(16 + v + h * 8) << 9) + f * 4);
    }

    bf16x8 a[8], b[8];
#pragma unroll
    for (int mt = 0; mt < 8; ++mt)
      a[mt] = *(const bf16x8*)(Ul + (mt * 16 + l15) * 32 + g * 8);
#pragma unroll
    for (int i = 0; i < 8; ++i) {
      int p = (wid * 8 + i) * 16 + l15;
      b[i] = *(const bf16x8*)(slab + p * 32 + g * 8);
    }

    int w = v0 + half * 16 + l15;    // node index
#pragma unroll
    for (int mt = 0; mt < 8; ++mt) {
      int o = mt * 4 + g;            // D row R = mt*16 + g*4 + reg; jj = reg
      u16* cbase = C + ((size_t)(nol_base + o) * 512 + l0) * 2048 + (size_t)w * 4;
#pragma unroll
      for (int i = 0; i < 8; ++i) {
        f32x4 z = {0.f, 0.f, 0.f, 0.f};
        f32x4 acc = __builtin_amdgcn_mfma_f32_16x16x32_bf16(a[mt], b[i], z, 0, 0, 0);
        int nt = wid * 8 + i;        // l within block
        u32 lo = (u32)f2b(acc[0]) | ((u32)f2b(acc[1]) << 16);
        u32 hi = (u32)f2b(acc[2]) | ((u32)f2b(acc[3]) << 16);
        *(uint2*)(cbase + (size_t)nt * 2048) = make_uint2(lo, hi);
      }
    }
    __syncthreads();   // slab consumed; safe to overwrite for half 1
  }
}

// ---------------------------------------------------------------------------
// P2 (k_gemm): per (n,o): y[512,512] = G[512,2048] @ C[no][*,2048]^T + b.
// 256x256 tile, BK=64, 8 waves. R6 schedule VERBATIM (staging, barriers,
// vmcnt(4) ledger, LGKM0 placement all unchanged — best measured structure).
// R10->R11: math ported to v_mfma_f32_32x32x16_bf16 (2382 vs 2075 TF ubench;
// 32 MFMA/K-tile/wave vs 64 -> pipe work -13%, issue slots halved).
// Frags per wave: 4m x 2n of 32x32; K=64 = 4 k-steps of 16.
// A/B lane layout: m(n)=lane&31, k=(lane>>5)*8+b (blocked-8, consistent with
// the verified blocked-8 of 16x16x32). C/D: col=lane&31,
// row=(reg&3)+8*(reg>>2)+4*(lane>>5)  [m101-verified].
// LDS slot index for k-step kt: kt*2+(lane>>5), same XOR swizzle.
// ---------------------------------------------------------------------------
#define BAR   asm volatile("s_barrier" ::: "memory")
#define LGKM0 do { asm volatile("s_waitcnt lgkmcnt(0)" ::: "memory");          \
                   __builtin_amdgcn_sched_barrier(0); } while (0)
#define VM4   do { asm volatile("s_waitcnt vmcnt(4)" ::: "memory");            \
                   __builtin_amdgcn_sched_barrier(0); } while (0)
#define VM0   do { asm volatile("s_waitcnt vmcnt(0)" ::: "memory");            \
                   __builtin_amdgcn_sched_barrier(0); } while (0)

__global__ __launch_bounds__(512, 2) void k_gemm(const u16* __restrict__ G,
                                                 const u16* __restrict__ C,
                                                 const float* __restrict__ bias,
                                                 float* __restrict__ y,
                                                 int n0) {
  __shared__ u16 lds[65536];   // 128 KB. Bytes: A(b)=b*32768, B(b)=65536+b*32768
  int t = threadIdx.x;
  int rb = blockIdx.x;
  int chunk = gridDim.x >> 3;
  int virt = (rb & 7) * chunk + (rb >> 3);
  int nn = n0 + (virt >> 7);
  int r7 = virt & 127;
  int o  = r7 >> 2;
  int vt = (r7 >> 1) & 1, lt = r7 & 1;
  int v0 = vt << 8, l0 = lt << 8;
  const u16* Cp = C + (size_t)((nn - n0) * 32 + o) * (512 * 2048);

  int lane = t & 63, wid = t >> 6;
  int wm = wid >> 2, wn = wid & 3;          // 2M x 4N wave grid

  // staging source (pre-swizzled slot), linear LDS dest  (unchanged)
  int rr = t >> 3;                          // 0..63
  int sp = (t & 7) ^ (rr & 7);
  const u16* gA = G  + (size_t)(v0 + rr) * 2048 + sp * 8;
  const u16* gB = Cp + (size_t)(l0 + rr) * 2048 + sp * 8;
  char* ldsw = (char*)lds + (wid << 10);

#define STGA(b, T, h)                                                        \
  do {                                                                       \
    const u16* s_ = gA + (size_t)(h) * 262144 + (size_t)(T) * 64;            \
    gld16(s_,          ldsw + (b) * 32768 + (h) * 16384);                    \
    gld16(s_ + 131072, ldsw + (b) * 32768 + (h) * 16384 + 8192);             \
  } while (0)
#define STGB(b, T, h)                                                        \
  do {                                                                       \
    const u16* s_ = gB + (size_t)(h) * 262144 + (size_t)(T) * 64;            \
    gld16(s_,          ldsw + 65536 + (b) * 32768 + (h) * 16384);            \
    gld16(s_ + 131072, ldsw + 65536 + (b) * 32768 + (h) * 16384 + 8192);     \
  } while (0)

  // swizzled fragment read offsets (32x32x16 operands)
  int l31 = lane & 31, lh = lane >> 5;      // lane half
  int sxk[4];
#pragma unroll
  for (int kt = 0; kt < 4; ++kt)
    sxk[kt] = (((kt * 2 + lh) ^ (lane & 7)) << 4);
  int aoff = (wm * 128 + l31) * 128;        // bytes (row stride 128B)
  int boff = (wn * 64 + l31) * 128;
  const char* ldsc = (const char*)lds;

  bf16x8 af[4][4], bf[2][4];                // [frag][k-step]
#define RDK0(b)                                                              \
  do {                                                                       \
    _Pragma("unroll") for (int m = 0; m < 4; ++m) {                          \
      af[m][0] = *(const bf16x8*)(ldsc + (b) * 32768 + aoff + m * 4096 + sxk[0]); \
      af[m][1] = *(const bf16x8*)(ldsc + (b) * 32768 + aoff + m * 4096 + sxk[1]); \
    }                                                                        \
    _Pragma("unroll") for (int n = 0; n < 2; ++n) {                          \
      bf[n][0] = *(const bf16x8*)(ldsc + 65536 + (b) * 32768 + boff + n * 4096 + sxk[0]); \
      bf[n][1] = *(const bf16x8*)(ldsc + 65536 + (b) * 32768 + boff + n * 4096 + sxk[1]); \
    }                                                                        \
  } while (0)
#define RDK1(b)                                                              \
  do {                                                                       \
    _Pragma("unroll") for (int m = 0; m < 4; ++m) {                          \
      af[m][2] = *(const bf16x8*)(ldsc + (b) * 32768 + aoff + m * 4096 + sxk[2]); \
      af[m][3] = *(const bf16x8*)(ldsc + (b) * 32768 + aoff + m * 4096 + sxk[3]); \
    }                                                                        \
    _Pragma("unroll") for (int n = 0; n < 2; ++n) {                          \
      bf[n][2] = *(const bf16x8*)(ldsc + 65536 + (b) * 32768 + boff + n * 4096 + sxk[2]); \
      bf[n][3] = *(const bf16x8*)(ldsc + 65536 + (b) * 32768 + boff + n * 4096 + sxk[3]); \
    }                                                                        \
  } while (0)

  f32x16 acc[4][2];
#pragma unroll
  for (int i = 0; i < 4; ++i)
#pragma unroll
    for (int j = 0; j < 2; ++j)
#pragma unroll
      for (int q = 0; q < 16; ++q) acc[i][j][q] = 0.f;

  // CLUSTER(mh, kp): m-frags {mh*2, mh*2+1} x 2 n-frags x k-steps {kp*2, kp*2+1}
#define CLUSTER(mh, kp)                                                      \
  do {                                                                       \
    __builtin_amdgcn_s_setprio(1);                                           \
    _Pragma("unroll") for (int m = 0; m < 2; ++m)                            \
    _Pragma("unroll") for (int n = 0; n < 2; ++n)                            \
    _Pragma("unroll") for (int kk = 0; kk < 2; ++kk)                         \
      acc[(mh) * 2 + m][n] = __builtin_amdgcn_mfma_f32_32x32x16_bf16(        \
          af[(mh) * 2 + m][(kp) * 2 + kk], bf[n][(kp) * 2 + kk],             \
          acc[(mh) * 2 + m][n], 0, 0, 0);                                    \
    __builtin_amdgcn_s_setprio(0);                                           \
  } while (0)

  // prologue: tile0 (buf0) full + tile1 (buf1) Ah0,Ah1  (6 half-tiles)
  STGA(0, 0, 0); STGA(0, 0, 1); STGB(0, 0, 0); STGB(0, 0, 1);
  STGA(1, 1, 0); STGA(1, 1, 1);
  VM4;            // newest 4 = tile1's A halves -> tile0 fully landed
  BAR;

  for (int tt = 0; tt < 16; ++tt) {
    int t1 = 2 * tt + 1;
    int T2 = 2 * tt + 2;     // next buf0 tile
    int T3 = 2 * tt + 3;     // next buf1 tile
    bool more = (tt < 15);
    // ph1: reads k-steps 0,1 (buf0); stage t1.Bh0
    RDK0(0);
    STGB(1, t1, 0);
    BAR; CLUSTER(0, 0); BAR;
    // ph2: reads k-steps 2,3 (buf0); stage t1.Bh1; trailing LGKM0 (WAR-safe)
    RDK1(0);
    STGB(1, t1, 1);
    BAR; CLUSTER(1, 0); LGKM0; BAR;
    // ph3: stage T2.Ah0
    if (more) STGA(0, T2, 0);
    BAR; CLUSTER(0, 1); BAR;
    // ph4: stage T2.Ah1; VM4 -> t1 fully landed (12 outstanding, keep 4)
    if (more) {
      STGA(0, T2, 1);
      VM4;
    } else {
      VM0;                   // tail: drain t1's 8 before ph5 reads buf1
    }
    BAR; CLUSTER(1, 1); BAR;
    // ph5: reads k-steps 0,1 (buf1); stage T2.Bh0
    RDK0(1);
    if (more) STGB(0, T2, 0);
    BAR; CLUSTER(0, 0); BAR;
    // ph6: reads k-steps 2,3 (buf1); stage T2.Bh1; trailing LGKM0 (WAR-safe)
    RDK1(1);
    if (more) STGB(0, T2, 1);
    BAR; CLUSTER(1, 0); LGKM0; BAR;
    // ph7: stage T3.Ah0
    if (more) STGA(1, T3, 0);
    BAR; CLUSTER(0, 1); BAR;
    // ph8: stage T3.Ah1; VM4 -> T2 fully landed
    if (more) {
      STGA(1, T3, 1);
      VM4;
    }
    BAR; CLUSTER(1, 1); BAR;
  }
#undef STGA
#undef STGB
#undef RDK0
#undef RDK1
#undef CLUSTER

  // epilogue: C/D 32x32 layout — col(l)=lane&31, row(v)=(q&3)+8*(q>>2)+4*lh
  float bo = bias[o];
#pragma unroll
  for (int fm = 0; fm < 4; ++fm)
#pragma unroll
    for (int fn = 0; fn < 2; ++fn)
#pragma unroll
      for (int q = 0; q < 16; ++q) {
        int vv = v0 + wm * 128 + fm * 32 + (q & 3) + ((q >> 2) << 3) + (lh << 2);
        int ll = l0 + wn * 64 + fn * 32 + l31;
        size_t idx = (((size_t)(nn * 32 + o) * 512 + vv) << 9) + ll;
        y[idx] = acc[fm][fn][q] + bo;
      }
}

// ---------------------------------------------------------------------------
extern "C" void kernel_launch(void* const* d_in, const int* in_sizes, int n_in,
                              void* d_out, int out_size, void* d_ws, size_t ws_size,
                              hipStream_t stream) {
  (void)in_sizes; (void)n_in; (void)out_size;
  const float* x    = (const float*)d_in[0];
  const float* adj  = (const float*)d_in[1];
  const float* W    = (const float*)d_in[2];
  const float* bias = (const float*)d_in[3];
  float* y = (float*)d_out;
  char* ws = (char*)d_ws;

  u16*   G  = (u16*)(ws);                  // 512*2048*2      = 2,097,152
  float* Af = (float*)(ws + 2097152);      // 512*512*4       = 1,048,576
  float* A2 = (float*)(ws + 3145728);      // 1,048,576
  float* A3 = (float*)(ws + 4194304);      // 1,048,576
  u16*   U  = (u16*)(ws + 5242880);        // 128*32*2        = 8,192
  u16*   C  = (u16*)(ws + 5251072);        // per-n: 32*512*2048*2 = 67,108,864
  const size_t fixed = 5251072;
  const size_t per_n = (size_t)32 * 512 * 2048 * 2;

  int grp = 0;
  const int cands[2] = {2, 1};
  for (int i = 0; i < 2; ++i)
    if (fixed + (size_t)cands[i] * per_n <= ws_size) { grp = cands[i]; break; }
  if (!grp) return;

  k_norm<<<dim3(512), dim3(256), 0, stream>>>(adj, Af);
  k_pow <<<dim3(128), dim3(256), 0, stream>>>(Af, Af, A2);
  k_pow <<<dim3(128), dim3(256), 0, stream>>>(A2, Af, A3);
  k_pack<<<dim3(512), dim3(256), 0, stream>>>(Af, A2, A3, G);
  k_u   <<<dim3(1),   dim3(128), 0, stream>>>(W, U);

  for (int n0 = 0; n0 < 8; n0 += grp) {
    k_mix <<<dim3(grp * 256), dim3(256), 0, stream>>>(x, U, C, n0);
    k_gemm<<<dim3(grp * 128), dim3(512), 0, stream>>>(G, C, bias, y, n0);
  }
}

// Round 12
// 478.005 us; speedup vs baseline: 1.0842x; 1.0842x over previous
//
#include <hip/hip_runtime.h>
#include <cstdint>
#include <cstddef>

typedef unsigned short u16;
typedef unsigned int   u32;
typedef __attribute__((ext_vector_type(8))) short bf16x8;   // 8 bf16 in 4 VGPRs
typedef __attribute__((ext_vector_type(4))) float f32x4;

#define ALPHA 0.05f
#define OMA   0.95f

__device__ __forceinline__ u16 f2b(float f) {
  u32 u = __float_as_uint(f);
  u = (u + 0x7fffu + ((u >> 16) & 1u)) >> 16;   // RNE f32->bf16
  return (u16)u;
}

__device__ __forceinline__ void gld16(const void* g, void* l) {
  __builtin_amdgcn_global_load_lds((const __attribute__((address_space(1))) u32*)g,
                                   (__attribute__((address_space(3))) u32*)l, 16, 0, 0);
}

// ---------------------------------------------------------------------------
// K0: Abar = 0.95 * rownorm(adj + I) -> fp32 Af
// ---------------------------------------------------------------------------
__global__ __launch_bounds__(256) void k_norm(const float* __restrict__ adj,
                                              float* __restrict__ Af) {
  int v = blockIdx.x;      // 512
  int t = threadIdx.x;     // 256
  float a0 = adj[(size_t)v * 512 + t]       + (t == v ? 1.f : 0.f);
  float a1 = adj[(size_t)v * 512 + t + 256] + (t + 256 == v ? 1.f : 0.f);
  float s = a0 + a1;
  for (int off = 32; off; off >>= 1) s += __shfl_down(s, off);
  __shared__ float ws4[4];
  if ((t & 63) == 0) ws4[t >> 6] = s;
  __syncthreads();
  float inv = OMA / (ws4[0] + ws4[1] + ws4[2] + ws4[3]);
  Af[(size_t)v * 512 + t]       = a0 * inv;
  Af[(size_t)v * 512 + t + 256] = a1 * inv;
}

// ---------------------------------------------------------------------------
// K1/K2: P = L @ R (512x512 fp32)
// ---------------------------------------------------------------------------
__global__ __launch_bounds__(256) void k_pow(const float* __restrict__ L,
                                             const float* __restrict__ R,
                                             float* __restrict__ Pf) {
  __shared__ float lrow[4][512];
  int r0 = blockIdx.x * 4;   // 128 blocks
  int t = threadIdx.x;       // 256
  for (int i = t; i < 4 * 512; i += 256)
    lrow[i >> 9][i & 511] = L[(size_t)(r0 + (i >> 9)) * 512 + (i & 511)];
  __syncthreads();
  float acc[4][2] = {};
  for (int k = 0; k < 512; ++k) {
    float rk0 = R[(size_t)k * 512 + t];
    float rk1 = R[(size_t)k * 512 + t + 256];
#pragma unroll
    for (int r = 0; r < 4; ++r) {
      float lv = lrow[r][k];
      acc[r][0] += lv * rk0;
      acc[r][1] += lv * rk1;
    }
  }
  for (int r = 0; r < 4; ++r) {
    Pf[(size_t)(r0 + r) * 512 + t]       = acc[r][0];
    Pf[(size_t)(r0 + r) * 512 + t + 256] = acc[r][1];
  }
}

// ---------------------------------------------------------------------------
// K3: assemble G[v][w*4+jj] = {I, Abar, Abar^2, Abar^3}[v][w]  (bf16, 512x2048)
// ---------------------------------------------------------------------------
__global__ __launch_bounds__(256) void k_pack(const float* __restrict__ A1,
                                              const float* __restrict__ A2,
                                              const float* __restrict__ A3,
                                              u16* __restrict__ G) {
  int v = blockIdx.x;      // 512
  int t = threadIdx.x;     // 256
#pragma unroll
  for (int h = 0; h < 2; ++h) {
    int w = t + h * 256;
    size_t i = (size_t)v * 512 + w;
    u32 lo = (u32)(w == v ? 0x3F80u : 0u) | ((u32)f2b(A1[i]) << 16);
    u32 hi = (u32)f2b(A2[i]) | ((u32)f2b(A3[i]) << 16);
    *(uint2*)(G + (size_t)v * 2048 + w * 4) = make_uint2(lo, hi);
  }
}

// ---------------------------------------------------------------------------
// K4: U[R=o*4+jj][c]  (bf16, 128x32) from W[32][128]
// ---------------------------------------------------------------------------
__global__ void k_u(const float* __restrict__ W, u16* __restrict__ U) {
  int R = threadIdx.x;   // 128
  int o = R >> 2, j = R & 3;
  for (int c = 0; c < 32; ++c) {
    float w0 = W[o * 128 + c];
    float w1 = W[o * 128 + 32 + c];
    float w2 = W[o * 128 + 64 + c];
    float w3 = W[o * 128 + 96 + c];
    float u;
    if (j == 0)      u = w0 + ALPHA * (w1 + w2 + w3);
    else if (j == 1) u = w1 + ALPHA * (w2 + w3);
    else if (j == 2) u = w2 + ALPHA * w3;
    else             u = w3;
    U[R * 32 + c] = f2b(u);
  }
}

// ---------------------------------------------------------------------------
// P1 (k_mix): C_jj = U_jj @ x; lane's 4 regs (jj=0..3) -> one 8-B store.
// Two v-blocks per block with reg pipeline (R9, best measured).
// ---------------------------------------------------------------------------
__global__ __launch_bounds__(256) void k_mix(const float* __restrict__ x,
                                             const u16* __restrict__ Uw,
                                             u16* __restrict__ C,
                                             int n0) {
  __shared__ u16 slab[512 * 32];   // [p][c], p = l*16 + v   (32 KB)
  __shared__ u16 Ul[128 * 32];     // [R][c]                 (8 KB)
  int t = threadIdx.x;
  int chunk = gridDim.x >> 3;
  int rb = blockIdx.x;
  int vp = (rb & 7) * chunk + (rb >> 3);
  int tile0 = vp * 2;              // even: pair shares n and l0, v0 and v0+16
  int q  = tile0 & 511;
  int n  = n0 + (tile0 >> 9);
  int v0 = (q & 31) << 4;          // v-block of 16 (even slot)
  int l0 = (q >> 5) << 5;          // l-block of 32

  gld16(Uw + t * 8,        (char*)Ul + ((t >> 6) << 10));
  gld16(Uw + 2048 + t * 8, (char*)Ul + 4096 + ((t >> 6) << 10));

  int c = t & 31;
  int v = t >> 5;   // 0..7
  const float* xbase = x + (((size_t)(n * 32 + c) * 512 + v0) << 9) + l0;

  // preload tile A (v0) into regs
  float4 r[16];
#pragma unroll
  for (int h = 0; h < 2; ++h)
#pragma unroll
    for (int f = 0; f < 8; ++f)
      r[h * 8 + f] = *(const float4*)(xbase + ((size_t)(v + h * 8) << 9) + f * 4);

  int lane = t & 63, wid = t >> 6;
  int l15 = lane & 15, g = lane >> 4;
  int nol_base = (n - n0) * 32;

  for (int half = 0; half < 2; ++half) {
    // regs -> slab (bf16, [p][c] with p = l*16 + v)
#pragma unroll
    for (int h = 0; h < 2; ++h)
#pragma unroll
      for (int f = 0; f < 8; ++f) {
        float4 d = r[h * 8 + f];
        int vv = v + h * 8;
        int p = (f * 4) * 16 + vv;
        slab[(p + 0)  * 32 + c] = f2b(d.x);
        slab[(p + 16) * 32 + c] = f2b(d.y);
        slab[(p + 32) * 32 + c] = f2b(d.z);
        slab[(p + 48) * 32 + c] = f2b(d.w);
      }
    __syncthreads();   // slab ready (also drains U gld16 on half 0)

    if (half == 0) {
      // issue tile B (v0+16) loads; they land under A's compute/stores
#pragma unroll
      for (int h = 0; h < 2; ++h)
#pragma unroll
        for (int f = 0; f < 8; ++f)
          r[h * 8 + f] = *(const float4*)(xbase + ((size_t)(16 + v + h * 8) << 9) + f * 4);
    }

    bf16x8 a[8], b[8];
#pragma unroll
    for (int mt = 0; mt < 8; ++mt)
      a[mt] = *(const bf16x8*)(Ul + (mt * 16 + l15) * 32 + g * 8);
#pragma unroll
    for (int i = 0; i < 8; ++i) {
      int p = (wid * 8 + i) * 16 + l15;
      b[i] = *(const bf16x8*)(slab + p * 32 + g * 8);
    }

    int w = v0 + half * 16 + l15;    // node index
#pragma unroll
    for (int mt = 0; mt < 8; ++mt) {
      int o = mt * 4 + g;            // D row R = mt*16 + g*4 + reg; jj = reg
      u16* cbase = C + ((size_t)(nol_base + o) * 512 + l0) * 2048 + (size_t)w * 4;
#pragma unroll
      for (int i = 0; i < 8; ++i) {
        f32x4 z = {0.f, 0.f, 0.f, 0.f};
        f32x4 acc = __builtin_amdgcn_mfma_f32_16x16x32_bf16(a[mt], b[i], z, 0, 0, 0);
        int nt = wid * 8 + i;        // l within block
        u32 lo = (u32)f2b(acc[0]) | ((u32)f2b(acc[1]) << 16);
        u32 hi = (u32)f2b(acc[2]) | ((u32)f2b(acc[3]) << 16);
        *(uint2*)(cbase + (size_t)nt * 2048) = make_uint2(lo, hi);
      }
    }
    __syncthreads();   // slab consumed; safe to overwrite for half 1
  }
}

// ---------------------------------------------------------------------------
// P2 (k_gemm): per (n,o): y[512,512] = G[512,2048] @ C[no][*,2048]^T + b.
// 256x256 tile, BK=64, 8-phase counted-vmcnt pipeline. R6 schedule verbatim
// (best measured: 275 us @ 16x16x32; the 32x32x16 port regressed — reverted).
// ---------------------------------------------------------------------------
#define BAR   asm volatile("s_barrier" ::: "memory")
#define LGKM0 do { asm volatile("s_waitcnt lgkmcnt(0)" ::: "memory");          \
                   __builtin_amdgcn_sched_barrier(0); } while (0)
#define VM4   do { asm volatile("s_waitcnt vmcnt(4)" ::: "memory");            \
                   __builtin_amdgcn_sched_barrier(0); } while (0)
#define VM0   do { asm volatile("s_waitcnt vmcnt(0)" ::: "memory");            \
                   __builtin_amdgcn_sched_barrier(0); } while (0)

__global__ __launch_bounds__(512, 2) void k_gemm(const u16* __restrict__ G,
                                                 const u16* __restrict__ C,
                                                 const float* __restrict__ bias,
                                                 float* __restrict__ y,
                                                 int n0) {
  __shared__ u16 lds[65536];   // 128 KB. Bytes: A(b)=b*32768, B(b)=65536+b*32768
  int t = threadIdx.x;
  int rb = blockIdx.x;
  int chunk = gridDim.x >> 3;
  int virt = (rb & 7) * chunk + (rb >> 3);
  int nn = n0 + (virt >> 7);
  int r7 = virt & 127;
  int o  = r7 >> 2;
  int vt = (r7 >> 1) & 1, lt = r7 & 1;
  int v0 = vt << 8, l0 = lt << 8;
  const u16* Cp = C + (size_t)((nn - n0) * 32 + o) * (512 * 2048);

  int lane = t & 63, wid = t >> 6;
  int l15 = lane & 15, g = lane >> 4;
  int wm = wid >> 2, wn = wid & 3;          // 2M x 4N wave grid

  // staging source (pre-swizzled slot), linear LDS dest
  int rr = t >> 3;                          // 0..63
  int sp = (t & 7) ^ (rr & 7);
  const u16* gA = G  + (size_t)(v0 + rr) * 2048 + sp * 8;
  const u16* gB = Cp + (size_t)(l0 + rr) * 2048 + sp * 8;
  char* ldsw = (char*)lds + (wid << 10);

#define STGA(b, T, h)                                                        \
  do {                                                                       \
    const u16* s_ = gA + (size_t)(h) * 262144 + (size_t)(T) * 64;            \
    gld16(s_,          ldsw + (b) * 32768 + (h) * 16384);                    \
    gld16(s_ + 131072, ldsw + (b) * 32768 + (h) * 16384 + 8192);             \
  } while (0)
#define STGB(b, T, h)                                                        \
  do {                                                                       \
    const u16* s_ = gB + (size_t)(h) * 262144 + (size_t)(T) * 64;            \
    gld16(s_,          ldsw + 65536 + (b) * 32768 + (h) * 16384);            \
    gld16(s_ + 131072, ldsw + 65536 + (b) * 32768 + (h) * 16384 + 8192);     \
  } while (0)

  // swizzled fragment read offsets
  int sx0 = (g ^ (l15 & 7)) << 4;
  int sx1 = ((4 | g) ^ (l15 & 7)) << 4;
  int aoff = (wm * 128 + l15) * 128;        // bytes
  int boff = (wn * 64 + l15) * 128;
  const char* ldsc = (const char*)lds;

  bf16x8 af[8][2], bf[4][2];
#define RDK0(b)                                                              \
  do {                                                                       \
    _Pragma("unroll") for (int m = 0; m < 8; ++m)                            \
      af[m][0] = *(const bf16x8*)(ldsc + (b) * 32768 + aoff + m * 2048 + sx0); \
    _Pragma("unroll") for (int n = 0; n < 4; ++n)                            \
      bf[n][0] = *(const bf16x8*)(ldsc + 65536 + (b) * 32768 + boff + n * 2048 + sx0); \
  } while (0)
#define RDK1(b)                                                              \
  do {                                                                       \
    _Pragma("unroll") for (int m = 0; m < 8; ++m)                            \
      af[m][1] = *(const bf16x8*)(ldsc + (b) * 32768 + aoff + m * 2048 + sx1); \
    _Pragma("unroll") for (int n = 0; n < 4; ++n)                            \
      bf[n][1] = *(const bf16x8*)(ldsc + 65536 + (b) * 32768 + boff + n * 2048 + sx1); \
  } while (0)

  f32x4 acc[8][4];
#pragma unroll
  for (int i = 0; i < 8; ++i)
#pragma unroll
    for (int j = 0; j < 4; ++j) {
      f32x4 z = {0.f, 0.f, 0.f, 0.f};
      acc[i][j] = z;
    }

#define CLUSTER(mh, ks)                                                      \
  do {                                                                       \
    __builtin_amdgcn_s_setprio(1);                                           \
    _Pragma("unroll") for (int m = 0; m < 4; ++m)                            \
    _Pragma("unroll") for (int n = 0; n < 4; ++n)                            \
      acc[(mh) * 4 + m][n] = __builtin_amdgcn_mfma_f32_16x16x32_bf16(        \
          af[(mh) * 4 + m][ks], bf[n][ks], acc[(mh) * 4 + m][n], 0, 0, 0);   \
    __builtin_amdgcn_s_setprio(0);                                           \
  } while (0)

  // prologue: tile0 (buf0) full + tile1 (buf1) Ah0,Ah1  (6 half-tiles)
  STGA(0, 0, 0); STGA(0, 0, 1); STGB(0, 0, 0); STGB(0, 0, 1);
  STGA(1, 1, 0); STGA(1, 1, 1);
  VM4;            // newest 4 = tile1's A halves -> tile0 fully landed
  BAR;

  for (int tt = 0; tt < 16; ++tt) {
    int t1 = 2 * tt + 1;
    int T2 = 2 * tt + 2;     // next buf0 tile
    int T3 = 2 * tt + 3;     // next buf1 tile
    bool more = (tt < 15);
    // ph1: reads k0(buf0); stage t1.Bh0
    RDK0(0);
    STGB(1, t1, 0);
    BAR; CLUSTER(0, 0); BAR;
    // ph2: reads k1(buf0); stage t1.Bh1; trailing LGKM0 (buf0 WAR-safe)
    RDK1(0);
    STGB(1, t1, 1);
    BAR; CLUSTER(1, 0); LGKM0; BAR;
    // ph3: stage T2.Ah0
    if (more) STGA(0, T2, 0);
    BAR; CLUSTER(0, 1); BAR;
    // ph4: stage T2.Ah1; VM4 -> t1 fully landed (12 outstanding, keep 4)
    if (more) {
      STGA(0, T2, 1);
      VM4;
    } else {
      VM0;                   // tail: drain t1's 8 before ph5 reads buf1
    }
    BAR; CLUSTER(1, 1); BAR;
    // ph5: reads k0(buf1); stage T2.Bh0
    RDK0(1);
    if (more) STGB(0, T2, 0);
    BAR; CLUSTER(0, 0); BAR;
    // ph6: reads k1(buf1); stage T2.Bh1; trailing LGKM0 (buf1 WAR-safe)
    RDK1(1);
    if (more) STGB(0, T2, 1);
    BAR; CLUSTER(1, 0); LGKM0; BAR;
    // ph7: stage T3.Ah0
    if (more) STGA(1, T3, 0);
    BAR; CLUSTER(0, 1); BAR;
    // ph8: stage T3.Ah1; VM4 -> T2 fully landed
    if (more) {
      STGA(1, T3, 1);
      VM4;
    }
    BAR; CLUSTER(1, 1); BAR;
  }
#undef STGA
#undef STGB
#undef RDK0
#undef RDK1
#undef CLUSTER

  float bo = bias[o];
#pragma unroll
  for (int mm = 0; mm < 8; ++mm)
#pragma unroll
    for (int n = 0; n < 4; ++n)
#pragma unroll
      for (int q = 0; q < 4; ++q) {
        int vv = v0 + wm * 128 + mm * 16 + g * 4 + q;
        int ll = l0 + wn * 64 + n * 16 + l15;
        size_t idx = (((size_t)(nn * 32 + o) * 512 + vv) << 9) + ll;
        y[idx] = acc[mm][n][q] + bo;
      }
}

// ---------------------------------------------------------------------------
extern "C" void kernel_launch(void* const* d_in, const int* in_sizes, int n_in,
                              void* d_out, int out_size, void* d_ws, size_t ws_size,
                              hipStream_t stream) {
  (void)in_sizes; (void)n_in; (void)out_size;
  const float* x    = (const float*)d_in[0];
  const float* adj  = (const float*)d_in[1];
  const float* W    = (const float*)d_in[2];
  const float* bias = (const float*)d_in[3];
  float* y = (float*)d_out;
  char* ws = (char*)d_ws;

  u16*   G  = (u16*)(ws);                  // 512*2048*2      = 2,097,152
  float* Af = (float*)(ws + 2097152);      // 512*512*4       = 1,048,576
  float* A2 = (float*)(ws + 3145728);      // 1,048,576
  float* A3 = (float*)(ws + 4194304);      // 1,048,576
  u16*   U  = (u16*)(ws + 5242880);        // 128*32*2        = 8,192
  u16*   C  = (u16*)(ws + 5251072);        // per-n: 32*512*2048*2 = 67,108,864
  const size_t fixed = 5251072;
  const size_t per_n = (size_t)32 * 512 * 2048 * 2;

  int grp = 0;
  const int cands[2] = {2, 1};
  for (int i = 0; i < 2; ++i)
    if (fixed + (size_t)cands[i] * per_n <= ws_size) { grp = cands[i]; break; }
  if (!grp) return;

  k_norm<<<dim3(512), dim3(256), 0, stream>>>(adj, Af);
  k_pow <<<dim3(128), dim3(256), 0, stream>>>(Af, Af, A2);
  k_pow <<<dim3(128), dim3(256), 0, stream>>>(A2, Af, A3);
  k_pack<<<dim3(512), dim3(256), 0, stream>>>(Af, A2, A3, G);
  k_u   <<<dim3(1),   dim3(128), 0, stream>>>(W, U);

  for (int n0 = 0; n0 < 8; n0 += grp) {
    k_mix <<<dim3(grp * 256), dim3(256), 0, stream>>>(x, U, C, n0);
    k_gemm<<<dim3(grp * 128), dim3(512), 0, stream>>>(G, C, bias, y, n0);
  }
}